// Round 5
// baseline (70.079 us; speedup 1.0000x reference)
//
#include <hip/hip_runtime.h>

// Non-selective SSM, A diagonal => per-state scalar recurrence (exact):
//   g_i[t] = a_i*g_i[t-1] + cb_i*u[t],  y[t] = sum_i g_i[t],  cb_i = B_i*C_i
// R5: chunk-parallel scan in pure f32 (R1's proven arithmetic, 4x parallelism):
//   Phase A: per (ch,q) chunk of 512 steps, end-state from 0 init:
//            E[q,ch,i] = sum_t a^(511-t) B u[512q+t]
//   Phase B: S_0=0; M[q]=C*S_q; S_{q+1}=a^512*S_q+E[q]   (4 serial steps)
//   Phase C: R1 scan over the chunk with g init = M[q,ch,i]
// Fallback to single-kernel R1 scan if ws_size < 4MB.

#define NCH   2048
#define LSEQ  2048
#define NQ    4
#define QL    512            // LSEQ/NQ
#define E_OFF 0
#define M_OFF (2u*1024u*1024u)
#define WS_NEED (4u*1024u*1024u)

// ---------------- Phase A: chunk end-states ----------------
__global__ __launch_bounds__(256) void ssm_partial(const float* __restrict__ u,
                                                   const float* __restrict__ A,
                                                   const float* __restrict__ Bv,
                                                   float* __restrict__ E)
{
    const int lane = threadIdx.x & 63;
    const int wv   = threadIdx.x >> 6;
    const int widx = blockIdx.x * 4 + wv;       // 0..8191
    const int q    = widx & 3;
    const int ch   = widx >> 2;

    const float a = A[lane * 65];
    const float b = Bv[lane];
    const float* __restrict__ base = u + (size_t)ch * LSEQ + q * QL;

    float ur[8];
    #pragma unroll
    for (int blk = 0; blk < 8; ++blk) ur[blk] = base[blk * 64 + lane];

    float h = 0.f;
    #pragma unroll
    for (int blk = 0; blk < 8; ++blk){
        #pragma unroll
        for (int tt = 0; tt < 64; ++tt){
            float uv = __int_as_float(__builtin_amdgcn_readlane(__float_as_int(ur[blk]), tt));
            h = fmaf(a, h, b * uv);
        }
    }
    E[((size_t)q * NCH + ch) * 64 + lane] = h;
}

// ---------------- Phase B: combine across chunks ----------------
__global__ __launch_bounds__(256) void ssm_combine(const float* __restrict__ A,
                                                   const float* __restrict__ Cv,
                                                   const float* __restrict__ E,
                                                   float* __restrict__ M)
{
    const int tid = blockIdx.x * 256 + threadIdx.x;   // 0..131071
    const int i   = tid & 63;
    const int ch  = tid >> 6;

    const float a = A[i * 65];
    float a512 = a;
    #pragma unroll
    for (int s = 0; s < 9; ++s) a512 *= a512;         // a^(2^9) = a^512
    const float c = Cv[i];

    float S = 0.f;
    #pragma unroll
    for (int q = 0; q < NQ; ++q){
        const size_t off = ((size_t)q * NCH + ch) * 64 + i;
        M[off] = c * S;
        S = fmaf(a512, S, E[off]);
    }
}

// ---------------- Phase C: scan with injected initial state ----------------
__global__ __launch_bounds__(256) void ssm_scan(const float* __restrict__ u,
                                                const float* __restrict__ A,
                                                const float* __restrict__ Bv,
                                                const float* __restrict__ Cv,
                                                const float* __restrict__ M,
                                                float* __restrict__ y)
{
    __shared__ float tile[4][16][68];                 // 17408 B

    const int lane = threadIdx.x & 63;
    const int wv   = threadIdx.x >> 6;
    const int widx = blockIdx.x * 4 + wv;
    const int q    = widx & 3;
    const int ch   = widx >> 2;

    const float a  = A[lane * 65];
    const float cb = Bv[lane] * Cv[lane];
    const float* __restrict__ base = u + (size_t)ch * LSEQ + q * QL;
    float* __restrict__       yc   = y + (size_t)ch * LSEQ + q * QL;

    float g = M[((size_t)q * NCH + ch) * 64 + lane];  // C_i * S_q

    float (*tl)[68] = tile[wv];
    const int j    = lane & 15;
    const int part = lane >> 4;

    float ur[8];
    #pragma unroll
    for (int blk = 0; blk < 8; ++blk) ur[blk] = base[blk * 64 + lane];

    #pragma unroll
    for (int blk = 0; blk < 8; ++blk){
        #pragma unroll
        for (int sub = 0; sub < 4; ++sub){
            #pragma unroll
            for (int tt = 0; tt < 16; ++tt){
                float uv = __int_as_float(
                    __builtin_amdgcn_readlane(__float_as_int(ur[blk]), sub * 16 + tt));
                g = fmaf(a, g, cb * uv);
                tl[tt][lane] = g;
            }
            // same-wave LDS RAW; compiler inserts lgkmcnt waits (tile is wave-private)
            float4 v0 = *reinterpret_cast<const float4*>(&tl[j][16 * part + 0]);
            float4 v1 = *reinterpret_cast<const float4*>(&tl[j][16 * part + 4]);
            float4 v2 = *reinterpret_cast<const float4*>(&tl[j][16 * part + 8]);
            float4 v3 = *reinterpret_cast<const float4*>(&tl[j][16 * part + 12]);
            float v = ((v0.x + v0.y) + (v0.z + v0.w)) + ((v1.x + v1.y) + (v1.z + v1.w))
                    + ((v2.x + v2.y) + (v2.z + v2.w)) + ((v3.x + v3.y) + (v3.z + v3.w));
            v += __shfl_xor(v, 16, 64);
            v += __shfl_xor(v, 32, 64);
            if (lane < 16) yc[blk * 64 + sub * 16 + lane] = v;
        }
    }
}

// ---------------- Fallback: R1 proven single-kernel scan ----------------
__global__ __launch_bounds__(256, 1) void ssm_r1(const float* __restrict__ u,
                                                 const float* __restrict__ A,
                                                 const float* __restrict__ Bv,
                                                 const float* __restrict__ Cv,
                                                 float* __restrict__ y)
{
    __shared__ float tile[4][64][68];
    const int wave = threadIdx.x >> 6;
    const int lane = threadIdx.x & 63;
    const int ch   = blockIdx.x * 4 + wave;

    const float* __restrict__ uc = u + (size_t)ch * LSEQ;
    float* __restrict__       yc = y + (size_t)ch * LSEQ;

    const float a  = A[lane * 65];
    const float cb = Bv[lane] * Cv[lane];

    float g = 0.0f;
    float (*tl)[68] = tile[wave];

    for (int t0 = 0; t0 < LSEQ; t0 += 64){
        float ur = uc[t0 + lane];
        #pragma unroll
        for (int t = 0; t < 64; ++t){
            int   ui   = __builtin_amdgcn_readlane(__float_as_int(ur), t);
            float uval = __int_as_float(ui);
            g = fmaf(a, g, cb * uval);
            tl[t][lane] = g;
        }
        float ysum = 0.0f;
        #pragma unroll
        for (int i = 0; i < 64; i += 4){
            float4 v = *reinterpret_cast<const float4*>(&tl[lane][i]);
            ysum += (v.x + v.y) + (v.z + v.w);
        }
        yc[t0 + lane] = ysum;
    }
}

extern "C" void kernel_launch(void* const* d_in, const int* in_sizes, int n_in,
                              void* d_out, int out_size, void* d_ws, size_t ws_size,
                              hipStream_t stream)
{
    const float* u  = (const float*)d_in[0];
    const float* A  = (const float*)d_in[1];
    const float* Bv = (const float*)d_in[2];
    const float* Cv = (const float*)d_in[3];
    float*       yo = (float*)d_out;
    char*        ws = (char*)d_ws;

    if (ws_size >= WS_NEED){
        float* E = (float*)(ws + E_OFF);
        float* M = (float*)(ws + M_OFF);
        ssm_partial<<<NCH * NQ / 4, 256, 0, stream>>>(u, A, Bv, E);
        ssm_combine<<<NCH * 64 / 256, 256, 0, stream>>>(A, Cv, E, M);
        ssm_scan<<<NCH * NQ / 4, 256, 0, stream>>>(u, A, Bv, Cv, M, yo);
    } else {
        ssm_r1<<<NCH / 4, 256, 0, stream>>>(u, A, Bv, Cv, yo);
    }
}

// Round 7
// 61.920 us; speedup vs baseline: 1.1318x; 1.1318x over previous
//
#include <hip/hip_runtime.h>

// Non-selective SSM, A diagonal => exact per-state recurrence
//   h_i[t] = a_i h_i[t-1] + b_i u[t],  y[t] = sum_i c_i h_i[t]
// Scan in H-units (H = aH + u), weights cb_i = b_i*c_i applied at the reduce.
// R7 = clean R6 structure (no probes):
//   Phase A (ssm_partialH): per (ch,q) 512-step chunk end-state from 0 init.
//   Phase C (ssm_scanC): inline chunk-combine + scan; H staged through a
//     [64 state][20] float LDS tile with b128 writes/reads (conflict-minimal
//     quad-start distribution), cross-state reduce fully on VALU via DPP
//     (quad_perm + row_ror within 16-lane rows), float4 y stores.
// Fallback: proven R1 scan if ws_size < 4MB.

#define NCH   2048
#define LSEQ  2048
#define NQ    4
#define QL    512

#define WS_E    (2u*1024u*1024u)       // E_H [NQ][NCH][64] f32 = 2 MB
#define WS_NEED (4u*1024u*1024u)

__device__ inline float rlane(float v, int l){
    return __int_as_float(__builtin_amdgcn_readlane(__float_as_int(v), l));
}
template<int CTRL>
__device__ inline float dppadd(float v){
    int t = __builtin_amdgcn_mov_dpp(__float_as_int(v), CTRL, 0xF, 0xF, true);
    return v + __int_as_float(t);
}
// full sum over each 16-lane row: xor1, xor2 (quad_perm), ror4, ror8
__device__ inline float rowsum16(float v){
    v = dppadd<0xB1>(v);    // quad_perm [1,0,3,2]
    v = dppadd<0x4E>(v);    // quad_perm [2,3,0,1]
    v = dppadd<0x124>(v);   // row_ror:4
    v = dppadd<0x128>(v);   // row_ror:8
    return v;
}

// ---------------- Phase A: chunk end-states in H-units ----------------
__global__ __launch_bounds__(256) void ssm_partialH(const float* __restrict__ u,
                                                    const float* __restrict__ A,
                                                    float* __restrict__ E)
{
    const int lane = threadIdx.x & 63;
    const int wv   = threadIdx.x >> 6;
    const int widx = blockIdx.x * 4 + wv;
    const int q    = widx & 3;
    const int ch   = widx >> 2;

    const float a = A[lane * 65];
    const float* __restrict__ base = u + (size_t)ch * LSEQ + q * QL;

    float H = 0.f;
    #pragma unroll
    for (int blk = 0; blk < 8; ++blk){
        float ur = base[blk * 64 + lane];
        #pragma unroll
        for (int tt = 0; tt < 64; ++tt)
            H = fmaf(a, H, rlane(ur, tt));
    }
    E[((size_t)q * NCH + ch) * 64 + lane] = H;
}

// ---------------- Phase C: inline combine + scan + DPP reduce ----------------
__global__ __launch_bounds__(256) void ssm_scanC(const float* __restrict__ u,
                                                 const float* __restrict__ A,
                                                 const float* __restrict__ Bv,
                                                 const float* __restrict__ Cv,
                                                 const float* __restrict__ E,
                                                 float* __restrict__ y)
{
    __shared__ __align__(16) float tile[4][64][20];   // 20480 B

    const int lane = threadIdx.x & 63;
    const int wv   = threadIdx.x >> 6;
    const int widx = blockIdx.x * 4 + wv;
    const int q    = widx & 3;
    const int ch   = widx >> 2;

    const float a  = A[lane * 65];
    const float cb = Bv[lane] * Cv[lane];
    float a512 = a;
    #pragma unroll
    for (int s = 0; s < 9; ++s) a512 *= a512;   // a^512

    // inline combine: H-init for this chunk (q=0 -> 0)
    float H = 0.f;
    for (int qp = 0; qp < q; ++qp)
        H = fmaf(a512, H, E[((size_t)qp * NCH + ch) * 64 + lane]);

    const int sl = lane & 15, tg = lane >> 4;
    float cbw[4];
    #pragma unroll
    for (int ss = 0; ss < 4; ++ss) cbw[ss] = __shfl(cb, sl + 16 * ss, 64);

    float* const tl = &tile[wv][0][0];
    const float* __restrict__ base = u + (size_t)ch * LSEQ + q * QL;
    float* __restrict__       yc   = y + (size_t)ch * LSEQ + q * QL;

    #pragma unroll
    for (int blk = 0; blk < 8; ++blk){
        float ur = base[blk * 64 + lane];
        #pragma unroll
        for (int sub = 0; sub < 4; ++sub){
            // 16 scan steps -> 4 quads, b128 writes (conflict-minimal starts)
            #pragma unroll
            for (int tb = 0; tb < 4; ++tb){
                float4 hv;
                H = fmaf(a, H, rlane(ur, sub * 16 + tb * 4 + 0)); hv.x = H;
                H = fmaf(a, H, rlane(ur, sub * 16 + tb * 4 + 1)); hv.y = H;
                H = fmaf(a, H, rlane(ur, sub * 16 + tb * 4 + 2)); hv.z = H;
                H = fmaf(a, H, rlane(ur, sub * 16 + tb * 4 + 3)); hv.w = H;
                *(float4*)(tl + lane * 20 + tb * 4) = hv;
            }
            // weighted 4-state partials (b128 reads; same-wave RAW -> lgkmcnt)
            float px = 0.f, py = 0.f, pz = 0.f, pw = 0.f;
            #pragma unroll
            for (int ss = 0; ss < 4; ++ss){
                float4 hq = *(const float4*)(tl + (sl + 16 * ss) * 20 + tg * 4);
                px = fmaf(cbw[ss], hq.x, px);
                py = fmaf(cbw[ss], hq.y, py);
                pz = fmaf(cbw[ss], hq.z, pz);
                pw = fmaf(cbw[ss], hq.w, pw);
            }
            // cross-state reduce over sl: pure-VALU DPP within 16-lane rows
            px = rowsum16(px); py = rowsum16(py);
            pz = rowsum16(pz); pw = rowsum16(pw);
            if (sl == 0){
                float4 o; o.x = px; o.y = py; o.z = pz; o.w = pw;
                *(float4*)(yc + blk * 64 + sub * 16 + tg * 4) = o;
            }
        }
    }
}

// ---------------- fallback: proven R1 scan ----------------
__global__ __launch_bounds__(256, 1) void ssm_r1(const float* __restrict__ u,
                                                 const float* __restrict__ A,
                                                 const float* __restrict__ Bv,
                                                 const float* __restrict__ Cv,
                                                 float* __restrict__ y)
{
    __shared__ float tile[4][64][68];
    const int wave = threadIdx.x >> 6;
    const int lane = threadIdx.x & 63;
    const int ch   = blockIdx.x * 4 + wave;

    const float* __restrict__ uc = u + (size_t)ch * LSEQ;
    float* __restrict__       yc = y + (size_t)ch * LSEQ;

    const float a  = A[lane * 65];
    const float cb = Bv[lane] * Cv[lane];

    float g = 0.0f;
    float (*tl)[68] = tile[wave];

    for (int t0 = 0; t0 < LSEQ; t0 += 64){
        float ur = uc[t0 + lane];
        #pragma unroll
        for (int t = 0; t < 64; ++t){
            g = fmaf(a, g, cb * rlane(ur, t));
            tl[t][lane] = g;
        }
        float ysum = 0.0f;
        #pragma unroll
        for (int i = 0; i < 64; i += 4){
            float4 v = *reinterpret_cast<const float4*>(&tl[lane][i]);
            ysum += (v.x + v.y) + (v.z + v.w);
        }
        yc[t0 + lane] = ysum;
    }
}

extern "C" void kernel_launch(void* const* d_in, const int* in_sizes, int n_in,
                              void* d_out, int out_size, void* d_ws, size_t ws_size,
                              hipStream_t stream)
{
    const float* u  = (const float*)d_in[0];
    const float* A  = (const float*)d_in[1];
    const float* Bv = (const float*)d_in[2];
    const float* Cv = (const float*)d_in[3];
    float*       yo = (float*)d_out;
    char*        ws = (char*)d_ws;

    if (ws_size >= WS_NEED){
        float* E = (float*)(ws + WS_E);
        ssm_partialH<<<NCH * NQ / 4, 256, 0, stream>>>(u, A, E);
        ssm_scanC<<<NCH * NQ / 4, 256, 0, stream>>>(u, A, Bv, Cv, E, yo);
    } else {
        ssm_r1<<<NCH / 4, 256, 0, stream>>>(u, A, Bv, Cv, yo);
    }
}